// Round 1
// baseline (1711.351 us; speedup 1.0000x reference)
//
#include <hip/hip_runtime.h>

#define B_   4
#define L_   160
#define D_   256
#define DP_  257
#define Q_   66049            // DP*DP
#define QPAD_ 66052           // T1 row stride (multiple of 4 for float4)
#define T2S_ 260              // T2 row stride (multiple of 4)
#define IJ_  25600            // L*L

// ---------------- Stage 1: T1[i][b*257+c] = sum_a l1p[i,a] * W[a,b,c] ----------------
// GEMM: M=160 (whole M in one block), N=66049 (64/block), K=256, bias row a=256 in init.
__global__ __launch_bounds__(256) void k_stage1(
    const float* __restrict__ l1, const float* __restrict__ W,
    float* __restrict__ T1, int n)
{
    const int tid = threadIdx.x;
    const int tx  = tid & 15;    // N sub-tile (4 cols each)
    const int ty  = tid >> 4;    // M group   (10 rows each)
    const int q0  = blockIdx.x * 64;

    __shared__ float As[32][161];  // [a][i], padded
    __shared__ float Bs[32][64];   // [a][q]

    const float* A = l1 + (size_t)n * L_ * D_;

    float acc[10][4];
    {   // init with bias row W[256][q]  (independent of i)
        const int q = q0 + tx * 4;
        const float* wb = W + (size_t)256 * Q_ + q;
        float v0, v1, v2, v3;
        if (q + 3 < Q_) { float4 t = *(const float4*)wb; v0 = t.x; v1 = t.y; v2 = t.z; v3 = t.w; }
        else {
            v0 = (q + 0 < Q_) ? wb[0] : 0.f;
            v1 = (q + 1 < Q_) ? wb[1] : 0.f;
            v2 = (q + 2 < Q_) ? wb[2] : 0.f;
            v3 = (q + 3 < Q_) ? wb[3] : 0.f;
        }
        #pragma unroll
        for (int m = 0; m < 10; ++m) { acc[m][0] = v0; acc[m][1] = v1; acc[m][2] = v2; acc[m][3] = v3; }
    }

    for (int a0 = 0; a0 < 256; a0 += 32) {
        __syncthreads();
        #pragma unroll
        for (int p = 0; p < 20; ++p) {          // 160*32 / 256
            int idx = tid + p * 256;
            int i = idx >> 5, aa = idx & 31;
            As[aa][i] = A[i * D_ + a0 + aa];
        }
        #pragma unroll
        for (int p = 0; p < 8; ++p) {           // 32*64 / 256
            int idx = tid + p * 256;
            int aa = idx >> 6, qq = idx & 63;
            int q = q0 + qq;
            Bs[aa][qq] = (q < Q_) ? W[(size_t)(a0 + aa) * Q_ + q] : 0.f;
        }
        __syncthreads();
        #pragma unroll
        for (int k = 0; k < 32; ++k) {
            const float4 bv = *(const float4*)&Bs[k][tx * 4];
            float av[10];
            #pragma unroll
            for (int m = 0; m < 10; ++m) av[m] = As[k][ty * 10 + m];
            #pragma unroll
            for (int m = 0; m < 10; ++m) {
                acc[m][0] = fmaf(av[m], bv.x, acc[m][0]);
                acc[m][1] = fmaf(av[m], bv.y, acc[m][1]);
                acc[m][2] = fmaf(av[m], bv.z, acc[m][2]);
                acc[m][3] = fmaf(av[m], bv.w, acc[m][3]);
            }
        }
    }

    #pragma unroll
    for (int m = 0; m < 10; ++m) {
        const int i = ty * 10 + m;
        const int q = q0 + tx * 4;
        float* dst = T1 + (size_t)i * QPAD_ + q;
        if (q + 3 < Q_) {
            *(float4*)dst = make_float4(acc[m][0], acc[m][1], acc[m][2], acc[m][3]);
        } else {
            if (q + 0 < Q_) dst[0] = acc[m][0];
            if (q + 1 < Q_) dst[1] = acc[m][1];
            if (q + 2 < Q_) dst[2] = acc[m][2];
            if (q + 3 < Q_) dst[3] = acc[m][3];
        }
    }
}

// ---------------- Stage 2: T2[(i,j)][c] = sum_b l2p[j,b] * T1[i][b*257+c] ----------------
// Batched over i: per block (c-tile, i): M=160 (j), N=64 (c), K=256, bias b=256 in init.
__global__ __launch_bounds__(256) void k_stage2(
    const float* __restrict__ l2, const float* __restrict__ T1,
    float* __restrict__ T2, int n)
{
    const int tid = threadIdx.x;
    const int tx  = tid & 15;
    const int ty  = tid >> 4;
    const int c0  = blockIdx.x * 64;
    const int i   = blockIdx.y;

    __shared__ float As[32][161];  // [b][j]
    __shared__ float Bs[32][64];   // [b][c]

    const float* A    = l2 + (size_t)n * L_ * D_;
    const float* Bmat = T1 + (size_t)i * QPAD_;   // [b*257 + c]

    float acc[10][4];
    {   // init with bias row T1[i][256*257 + c]   (l2p[j][256] == 1)
        const int c = c0 + tx * 4;
        const float* bb = Bmat + 256 * DP_ + c;
        float v0, v1, v2, v3;
        if (c + 3 < DP_) { float4 t = *(const float4*)bb; v0 = t.x; v1 = t.y; v2 = t.z; v3 = t.w; }
        else {
            v0 = (c + 0 < DP_) ? bb[0] : 0.f;
            v1 = (c + 1 < DP_) ? bb[1] : 0.f;
            v2 = (c + 2 < DP_) ? bb[2] : 0.f;
            v3 = (c + 3 < DP_) ? bb[3] : 0.f;
        }
        #pragma unroll
        for (int m = 0; m < 10; ++m) { acc[m][0] = v0; acc[m][1] = v1; acc[m][2] = v2; acc[m][3] = v3; }
    }

    for (int b0 = 0; b0 < 256; b0 += 32) {
        __syncthreads();
        #pragma unroll
        for (int p = 0; p < 20; ++p) {
            int idx = tid + p * 256;
            int j = idx >> 5, bb2 = idx & 31;
            As[bb2][j] = A[j * D_ + b0 + bb2];
        }
        #pragma unroll
        for (int p = 0; p < 8; ++p) {
            int idx = tid + p * 256;
            int bb2 = idx >> 6, cc = idx & 63;
            int c = c0 + cc;
            Bs[bb2][cc] = (c < DP_) ? Bmat[(size_t)(b0 + bb2) * DP_ + c] : 0.f;
        }
        __syncthreads();
        #pragma unroll
        for (int k = 0; k < 32; ++k) {
            const float4 bv = *(const float4*)&Bs[k][tx * 4];
            float av[10];
            #pragma unroll
            for (int m = 0; m < 10; ++m) av[m] = As[k][ty * 10 + m];
            #pragma unroll
            for (int m = 0; m < 10; ++m) {
                acc[m][0] = fmaf(av[m], bv.x, acc[m][0]);
                acc[m][1] = fmaf(av[m], bv.y, acc[m][1]);
                acc[m][2] = fmaf(av[m], bv.z, acc[m][2]);
                acc[m][3] = fmaf(av[m], bv.w, acc[m][3]);
            }
        }
    }

    #pragma unroll
    for (int m = 0; m < 10; ++m) {
        const int j = ty * 10 + m;
        const int c = c0 + tx * 4;
        float* dst = T2 + ((size_t)i * L_ + j) * T2S_ + c;
        if (c + 3 < DP_) {
            *(float4*)dst = make_float4(acc[m][0], acc[m][1], acc[m][2], acc[m][3]);
        } else {
            if (c + 0 < DP_) dst[0] = acc[m][0];
            if (c + 1 < DP_) dst[1] = acc[m][1];
            if (c + 2 < DP_) dst[2] = acc[m][2];
            if (c + 3 < DP_) dst[3] = acc[m][3];
        }
    }
}

// ---------------- Stage 3: out[n][(i,j)][k] = sum_c T2[(i,j)][c] * l3p[k][c] ----------------
// Per n: M=25600 (64/block), N=160 (whole N in block), K=256, bias c=256 in init.
__global__ __launch_bounds__(256) void k_stage3(
    const float* __restrict__ l3, const float* __restrict__ T2,
    float* __restrict__ outp, int n)
{
    const int tid = threadIdx.x;
    const int tx  = tid & 15;     // k sub (10 each: k = tx + 16*v)
    const int ty  = tid >> 4;     // ij sub (4 each)
    const int ij0 = blockIdx.x * 64;

    __shared__ float As[32][68];   // [c][ij], padded for aligned float4
    __shared__ float Bs[32][161];  // [c][k]

    const float* Bmat = l3 + (size_t)n * L_ * D_;

    float acc[4][10];
    #pragma unroll
    for (int u = 0; u < 4; ++u) {   // bias: l3p[k][256] == 1 -> + T2[ij][256]
        float t = T2[(size_t)(ij0 + ty * 4 + u) * T2S_ + 256];
        #pragma unroll
        for (int v = 0; v < 10; ++v) acc[u][v] = t;
    }

    for (int c0 = 0; c0 < 256; c0 += 32) {
        __syncthreads();
        #pragma unroll
        for (int p = 0; p < 8; ++p) {           // 64*32 / 256
            int idx = tid + p * 256;
            int ij = idx >> 5, cc = idx & 31;
            As[cc][ij] = T2[(size_t)(ij0 + ij) * T2S_ + c0 + cc];
        }
        #pragma unroll
        for (int p = 0; p < 20; ++p) {          // 160*32 / 256
            int idx = tid + p * 256;
            int kk = idx >> 5, cc = idx & 31;
            Bs[cc][kk] = Bmat[kk * D_ + c0 + cc];
        }
        __syncthreads();
        #pragma unroll
        for (int kc = 0; kc < 32; ++kc) {
            const float4 av4 = *(const float4*)&As[kc][ty * 4];
            float a4[4] = { av4.x, av4.y, av4.z, av4.w };
            float bv[10];
            #pragma unroll
            for (int v = 0; v < 10; ++v) bv[v] = Bs[kc][tx + 16 * v];
            #pragma unroll
            for (int u = 0; u < 4; ++u)
                #pragma unroll
                for (int v = 0; v < 10; ++v)
                    acc[u][v] = fmaf(a4[u], bv[v], acc[u][v]);
        }
    }

    float* dst = outp + (size_t)n * IJ_ * L_;
    #pragma unroll
    for (int u = 0; u < 4; ++u) {
        const int ij = ij0 + ty * 4 + u;
        #pragma unroll
        for (int v = 0; v < 10; ++v)
            dst[(size_t)ij * L_ + tx + 16 * v] = acc[u][v];
    }
}

extern "C" void kernel_launch(void* const* d_in, const int* in_sizes, int n_in,
                              void* d_out, int out_size, void* d_ws, size_t ws_size,
                              hipStream_t stream) {
    const float* l1 = (const float*)d_in[0];
    const float* l2 = (const float*)d_in[1];
    const float* l3 = (const float*)d_in[2];
    const float* W  = (const float*)d_in[3];
    float* outp = (float*)d_out;

    float* T1 = (float*)d_ws;                        // [160][66052]  = 42.3 MB
    float* T2 = T1 + (size_t)L_ * QPAD_;             // [25600][260]  = 26.6 MB

    const dim3 blk(256);
    for (int n = 0; n < B_; ++n) {
        k_stage1<<<dim3((Q_ + 63) / 64), blk, 0, stream>>>(l1, W, T1, n);
        k_stage2<<<dim3(5, L_), blk, 0, stream>>>(l2, T1, T2, n);
        k_stage3<<<dim3(IJ_ / 64), blk, 0, stream>>>(l3, T2, outp, n);
    }
}

// Round 2
// 1085.760 us; speedup vs baseline: 1.5762x; 1.5762x over previous
//
#include <hip/hip_runtime.h>

#define L_   160
#define D_   256
#define DP_  257
#define Q_   66049            // DP*DP
#define QT_  66176            // padded WT rows = 517*128
#define T1C_ 288              // T1 c-dim (padded rows)
#define T1B_ 264              // T1 b-dim (padded cols)
#define T1IS_ (T1C_*T1B_)     // 76032 per i
#define T2S_ 264              // T2 row stride
#define IJ_  25600

typedef unsigned short u16;
typedef unsigned int   u32;
typedef __attribute__((ext_vector_type(8))) short short8_t;  // 8 bf16 (4 VGPR)
typedef __attribute__((ext_vector_type(4))) float f32x4;     // acc frag

__device__ __forceinline__ float bf2f(u16 u){ union{u32 i; float f;} x; x.i=((u32)u)<<16; return x.f; }
__device__ __forceinline__ u16 f2bf(float f){ u32 u=__float_as_uint(f); return (u16)((u + 0x7FFFu + ((u>>16)&1u))>>16); }
__device__ __forceinline__ void split_store(float v, u16* hi, u16* lo, size_t idx){
    u16 h=f2bf(v); hi[idx]=h; lo[idx]=f2bf(v - bf2f(h));
}
__device__ __forceinline__ void gload16(const void* g, void* l){
    __builtin_amdgcn_global_load_lds((const __attribute__((address_space(1))) u32*)g,
                                     (__attribute__((address_space(3))) u32*)l, 16, 0, 0);
}

// ---------------- shared MFMA core: C[M][N] += A[M][K=256] * B[K][N] ----------------
// A rows (M) and B rows (N!) both stored k-contiguous; LDS tiles [rows][32k] = 64B rows.
// waves 2(M)x2(N); wave tile (16*MF) x (16*NF). Split-bf16: 3 MFMAs per frag pair.
template<int MF,int NF>
__device__ __forceinline__ void gemm_core(
    const u16* Ahi, const u16* Alo, int aStrideB,
    const u16* Bhi, const u16* Blo, int bStrideB,
    unsigned char* smem, f32x4 (&acc)[MF][NF])
{
    constexpr int AB = 32*MF*64;               // bytes of one A array in LDS
    constexpr int BB = 32*NF*64;
    constexpr int SLOTS = (2*AB+2*BB)/4096;    // 16B chunks per thread per K-tile
    const int tid=threadIdx.x, lane=tid&63, wv=tid>>6;
    const int wm=wv>>1, wn=wv&1;

    const unsigned char* src[SLOTS];
    #pragma unroll
    for(int s=0;s<SLOTS;++s){
        int byte=(s*256+tid)*16;
        int local; const unsigned char* base; int strideB;
        if(byte<AB)            { local=byte;          base=(const unsigned char*)Ahi; strideB=aStrideB; }
        else if(byte<2*AB)     { local=byte-AB;       base=(const unsigned char*)Alo; strideB=aStrideB; }
        else if(byte<2*AB+BB)  { local=byte-2*AB;     base=(const unsigned char*)Bhi; strideB=bStrideB; }
        else                   { local=byte-2*AB-BB;  base=(const unsigned char*)Blo; strideB=bStrideB; }
        int row=local>>6, ch=(local>>4)&3;
        src[s]=base + (size_t)row*strideB + ch*16;
    }
    const int kb16=(lane>>4)*16;
    for(int t=0;t<8;++t){
        #pragma unroll
        for(int s=0;s<SLOTS;++s){ gload16(src[s], smem + s*4096 + wv*1024); src[s]+=64; }
        __syncthreads();   // compiler drains vmcnt(0) before barrier -> LDS ready
        short8_t ah[MF], al[MF], bh[NF], bl[NF];
        #pragma unroll
        for(int m=0;m<MF;++m){
            int row=wm*16*MF + m*16 + (lane&15);
            ah[m]=*(const short8_t*)(smem + row*64 + kb16);
            al[m]=*(const short8_t*)(smem + AB + row*64 + kb16);
        }
        #pragma unroll
        for(int nn=0;nn<NF;++nn){
            int row=wn*16*NF + nn*16 + (lane&15);
            bh[nn]=*(const short8_t*)(smem + 2*AB + row*64 + kb16);
            bl[nn]=*(const short8_t*)(smem + 2*AB + BB + row*64 + kb16);
        }
        #pragma unroll
        for(int m=0;m<MF;++m)
        #pragma unroll
        for(int nn=0;nn<NF;++nn){
            acc[m][nn]=__builtin_amdgcn_mfma_f32_16x16x32_bf16(ah[m],bh[nn],acc[m][nn],0,0,0);
            acc[m][nn]=__builtin_amdgcn_mfma_f32_16x16x32_bf16(ah[m],bl[nn],acc[m][nn],0,0,0);
            acc[m][nn]=__builtin_amdgcn_mfma_f32_16x16x32_bf16(al[m],bh[nn],acc[m][nn],0,0,0);
        }
        __syncthreads();
    }
}

// ---------------- pre-pass: transpose+split W[a][q] -> WhiT/WloT[q][a<256] ----------------
__global__ __launch_bounds__(256) void k_splitWT(const float* __restrict__ W,
        u16* __restrict__ WhiT, u16* __restrict__ WloT)
{
    __shared__ float tile[64][65];
    const int tid=threadIdx.x;
    const int q0=blockIdx.x*64, a0=blockIdx.y*64;
    const int tq=tid&63, ta=tid>>6;
    #pragma unroll
    for(int r=0;r<16;++r){
        int a=a0 + r*4 + ta;
        int q=q0 + tq;
        tile[r*4+ta][tq] = (q<Q_) ? W[(size_t)a*Q_ + q] : 0.f;
    }
    __syncthreads();
    #pragma unroll
    for(int r=0;r<16;++r){
        int qlocal=r*4+ta;
        int q=q0+qlocal, a=a0+tq;
        float v=tile[tq][qlocal];
        size_t addr=(size_t)q*256 + a;
        u16 h=f2bf(v);
        WhiT[addr]=h;
        WloT[addr]=f2bf(v - bf2f(h));
    }
}

__global__ __launch_bounds__(256) void k_split(const float* __restrict__ in,
        u16* __restrict__ hi, u16* __restrict__ lo, int n)
{
    int idx=blockIdx.x*256+threadIdx.x;
    if(idx<n){ float v=in[idx]; u16 h=f2bf(v); hi[idx]=h; lo[idx]=f2bf(v - bf2f(h)); }
}

// ---------------- Stage 1: T1[i][c][b] = sum_a l1p[i,a]*W[a][b*257+c]  (transposed split store)
__global__ __launch_bounds__(256,2) void k_stage1(
    const u16* __restrict__ l1hi, const u16* __restrict__ l1lo,
    const u16* __restrict__ WhiT, const u16* __restrict__ WloT,
    const float* __restrict__ W,
    u16* __restrict__ T1hi, u16* __restrict__ T1lo)
{
    constexpr int MF=5, NF=4;
    __shared__ __attribute__((aligned(64))) unsigned char smem[(32*MF+32*NF)*128];
    const int tid=threadIdx.x, lane=tid&63, wv=tid>>6, wm=wv>>1, wn=wv&1;
    const int q0=blockIdx.x*128;

    f32x4 acc[MF][NF];
    #pragma unroll
    for(int nn=0;nn<NF;++nn){
        int q=q0 + wn*64 + nn*16 + (lane&15);
        float v=(q<Q_) ? W[(size_t)256*Q_ + q] : 0.f;   // bias row a=256
        #pragma unroll
        for(int m=0;m<MF;++m) acc[m][nn]=(f32x4){v,v,v,v};
    }

    gemm_core<MF,NF>(l1hi, l1lo, 512,
                     WhiT + (size_t)q0*256, WloT + (size_t)q0*256, 512,
                     smem, acc);

    #pragma unroll
    for(int m=0;m<MF;++m){
        int iRow=wm*80 + m*16 + (lane>>4)*4;
        #pragma unroll
        for(int nn=0;nn<NF;++nn){
            int q=q0 + wn*64 + nn*16 + (lane&15);
            u32 b=(u32)q/257u, c=(u32)q%257u;           // q>=Q_ -> b=257 pad col (harmless)
            #pragma unroll
            for(int r=0;r<4;++r){
                size_t addr=(size_t)(iRow+r)*T1IS_ + (size_t)c*T1B_ + b;
                split_store(acc[m][nn][r], T1hi, T1lo, addr);
            }
        }
    }
}

// ---------------- Stage 2: T2[(i,j)][c] = sum_b l2p[j,b]*T1[i][c][b] ----------------
template<int NF>
__global__ __launch_bounds__(256,2) void k_stage2(
    const u16* __restrict__ l2hi, const u16* __restrict__ l2lo,
    const u16* __restrict__ T1hi, const u16* __restrict__ T1lo,
    u16* __restrict__ T2hi, u16* __restrict__ T2lo, int c0base)
{
    constexpr int MF=5;
    __shared__ __attribute__((aligned(64))) unsigned char smem[(32*MF+32*NF)*128];
    const int tid=threadIdx.x, lane=tid&63, wv=tid>>6, wm=wv>>1, wn=wv&1;
    const int i=blockIdx.y;
    const int c0=c0base + blockIdx.x*32*NF;

    f32x4 acc[MF][NF];
    #pragma unroll
    for(int nn=0;nn<NF;++nn){
        int c=c0 + wn*16*NF + nn*16 + (lane&15);
        size_t ba=(size_t)i*T1IS_ + (size_t)c*T1B_ + 256;   // bias b=256
        float v=bf2f(T1hi[ba]) + bf2f(T1lo[ba]);
        #pragma unroll
        for(int m=0;m<MF;++m) acc[m][nn]=(f32x4){v,v,v,v};
    }

    gemm_core<MF,NF>(l2hi, l2lo, 512,
                     T1hi + (size_t)i*T1IS_ + (size_t)c0*T1B_,
                     T1lo + (size_t)i*T1IS_ + (size_t)c0*T1B_, T1B_*2,
                     smem, acc);

    #pragma unroll
    for(int m=0;m<MF;++m){
        int j0=wm*80 + m*16 + (lane>>4)*4;
        #pragma unroll
        for(int nn=0;nn<NF;++nn){
            int c=c0 + wn*16*NF + nn*16 + (lane&15);
            if(c<DP_){
                #pragma unroll
                for(int r=0;r<4;++r){
                    size_t addr=(size_t)(i*L_ + j0 + r)*T2S_ + c;
                    split_store(acc[m][nn][r], T2hi, T2lo, addr);
                }
            }
        }
    }
}

// ---------------- Stage 3: out[(i,j)][k] = sum_c T2[(i,j)][c]*l3p[k,c] ----------------
__global__ __launch_bounds__(256,2) void k_stage3(
    const u16* __restrict__ T2hi, const u16* __restrict__ T2lo,
    const u16* __restrict__ l3hi, const u16* __restrict__ l3lo,
    float* __restrict__ outp)
{
    constexpr int MF=4, NF=5;
    __shared__ __attribute__((aligned(64))) unsigned char smem[(32*MF+32*NF)*128];
    const int tid=threadIdx.x, lane=tid&63, wv=tid>>6, wm=wv>>1, wn=wv&1;
    const int ij0=blockIdx.x*128;

    f32x4 acc[MF][NF];
    #pragma unroll
    for(int m=0;m<MF;++m){
        float v[4];
        #pragma unroll
        for(int r=0;r<4;++r){
            int row=ij0 + wm*64 + m*16 + (lane>>4)*4 + r;
            size_t ba=(size_t)row*T2S_ + 256;               // bias c=256
            v[r]=bf2f(T2hi[ba]) + bf2f(T2lo[ba]);
        }
        #pragma unroll
        for(int nn=0;nn<NF;++nn) acc[m][nn]=(f32x4){v[0],v[1],v[2],v[3]};
    }

    gemm_core<MF,NF>(T2hi + (size_t)ij0*T2S_, T2lo + (size_t)ij0*T2S_, T2S_*2,
                     l3hi, l3lo, 512,
                     smem, acc);

    #pragma unroll
    for(int m=0;m<MF;++m){
        #pragma unroll
        for(int nn=0;nn<NF;++nn){
            int k=wn*80 + nn*16 + (lane&15);
            #pragma unroll
            for(int r=0;r<4;++r){
                int ij=ij0 + wm*64 + m*16 + (lane>>4)*4 + r;
                outp[(size_t)ij*L_ + k]=acc[m][nn][r];
            }
        }
    }
}

extern "C" void kernel_launch(void* const* d_in, const int* in_sizes, int n_in,
                              void* d_out, int out_size, void* d_ws, size_t ws_size,
                              hipStream_t stream) {
    const float* l1=(const float*)d_in[0];
    const float* l2=(const float*)d_in[1];
    const float* l3=(const float*)d_in[2];
    const float* W =(const float*)d_in[3];
    float* outp=(float*)d_out;
    (void)ws_size; (void)in_sizes; (void)n_in; (void)out_size;

    u16* p=(u16*)d_ws;
    u16* WhiT=p; p+=(size_t)QT_*256;
    u16* WloT=p; p+=(size_t)QT_*256;
    u16* l1hi=p; p+=640*256;  u16* l1lo=p; p+=640*256;
    u16* l2hi=p; p+=640*256;  u16* l2lo=p; p+=640*256;
    u16* l3hi=p; p+=640*256;  u16* l3lo=p; p+=640*256;
    u16* T1hi=p; p+=(size_t)L_*T1IS_;  u16* T1lo=p; p+=(size_t)L_*T1IS_;
    u16* T2hi=p; p+=(size_t)IJ_*T2S_;  u16* T2lo=p; p+=(size_t)IJ_*T2S_;

    k_splitWT<<<dim3(QT_/64, 4), 256, 0, stream>>>(W, WhiT, WloT);
    k_split<<<640, 256, 0, stream>>>(l1, l1hi, l1lo, 640*256);
    k_split<<<640, 256, 0, stream>>>(l2, l2hi, l2lo, 640*256);
    k_split<<<640, 256, 0, stream>>>(l3, l3hi, l3lo, 640*256);

    for(int n=0;n<4;++n){
        const size_t ofs=(size_t)n*L_*D_;
        k_stage1<<<517, 256, 0, stream>>>(l1hi+ofs, l1lo+ofs, WhiT, WloT, W, T1hi, T1lo);
        k_stage2<4><<<dim3(2,L_), 256, 0, stream>>>(l2hi+ofs, l2lo+ofs, T1hi, T1lo, T2hi, T2lo, 0);
        k_stage2<1><<<dim3(1,L_), 256, 0, stream>>>(l2hi+ofs, l2lo+ofs, T1hi, T1lo, T2hi, T2lo, 256);
        k_stage3<<<IJ_/128, 256, 0, stream>>>(T2hi, T2lo, l3hi+ofs, l3lo+ofs, outp + (size_t)n*IJ_*L_);
    }
}

// Round 3
// 487.105 us; speedup vs baseline: 3.5133x; 2.2290x over previous
//
#include <hip/hip_runtime.h>

#define L_   160
#define D_   256
#define DP_  257
#define Q_   66049            // DP*DP
#define QT_  66176            // padded WT rows = 517*128
#define T1B_ 256              // T1 b-dim (b=0..255; b=256 lives in T1bias)
#define T1R_ 288              // T1 c-rows (257 used, pad to 288)
#define T1IS_ (T1R_*T1B_)     // 73728 per i
#define TBS_ 288              // T1bias row stride (f32)
#define T2S_ 264              // T2 row stride
#define IJ_  25600

typedef unsigned short u16;
typedef unsigned int   u32;
typedef __attribute__((ext_vector_type(8))) short short8_t;  // 8 bf16 (4 VGPR)
typedef __attribute__((ext_vector_type(4))) float f32x4;     // acc frag

__device__ __forceinline__ float bf2f(u16 u){ union{u32 i; float f;} x; x.i=((u32)u)<<16; return x.f; }
__device__ __forceinline__ u16 f2bf(float f){ u32 u=__float_as_uint(f); return (u16)((u + 0x7FFFu + ((u>>16)&1u))>>16); }
__device__ __forceinline__ void split_store(float v, u16* hi, u16* lo, size_t idx){
    u16 h=f2bf(v); hi[idx]=h; lo[idx]=f2bf(v - bf2f(h));
}
__device__ __forceinline__ void gload16(const void* g, void* l){
    __builtin_amdgcn_global_load_lds((const __attribute__((address_space(1))) u32*)g,
                                     (__attribute__((address_space(3))) u32*)l, 16, 0, 0);
}

// ---------------- shared MFMA core: C[M][N] += A[M][K=256] * B[K][N] ----------------
// A rows (M) and B rows (N) both k-contiguous (64B per 32-k tile row); rows at affine
// stride from base. waves 2(M)x2(N); wave tile (16*MF) x (16*NF). Split-bf16: 3 MFMAs.
template<int MF,int NF>
__device__ __forceinline__ void gemm_core(
    const u16* Ahi, const u16* Alo, int aStrideB,
    const u16* Bhi, const u16* Blo, int bStrideB,
    unsigned char* smem, f32x4 (&acc)[MF][NF])
{
    constexpr int AB = 32*MF*64;               // bytes of one A array in LDS
    constexpr int BB = 32*NF*64;
    constexpr int SLOTS = (2*AB+2*BB)/4096;    // 16B chunks per thread per K-tile
    const int tid=threadIdx.x, lane=tid&63, wv=tid>>6;
    const int wm=wv>>1, wn=wv&1;

    const unsigned char* src[SLOTS];
    #pragma unroll
    for(int s=0;s<SLOTS;++s){
        int byte=(s*256+tid)*16;
        int local; const unsigned char* base; int strideB;
        if(byte<AB)            { local=byte;          base=(const unsigned char*)Ahi; strideB=aStrideB; }
        else if(byte<2*AB)     { local=byte-AB;       base=(const unsigned char*)Alo; strideB=aStrideB; }
        else if(byte<2*AB+BB)  { local=byte-2*AB;     base=(const unsigned char*)Bhi; strideB=bStrideB; }
        else                   { local=byte-2*AB-BB;  base=(const unsigned char*)Blo; strideB=bStrideB; }
        int row=local>>6, ch=(local>>4)&3;
        src[s]=base + (size_t)row*strideB + ch*16;
    }
    const int kb16=(lane>>4)*16;
    for(int t=0;t<8;++t){
        #pragma unroll
        for(int s=0;s<SLOTS;++s){ gload16(src[s], smem + s*4096 + wv*1024); src[s]+=64; }
        __syncthreads();   // compiler drains vmcnt(0) before barrier -> LDS ready
        short8_t ah[MF], al[MF], bh[NF], bl[NF];
        #pragma unroll
        for(int m=0;m<MF;++m){
            int row=wm*16*MF + m*16 + (lane&15);
            ah[m]=*(const short8_t*)(smem + row*64 + kb16);
            al[m]=*(const short8_t*)(smem + AB + row*64 + kb16);
        }
        #pragma unroll
        for(int nn=0;nn<NF;++nn){
            int row=wn*16*NF + nn*16 + (lane&15);
            bh[nn]=*(const short8_t*)(smem + 2*AB + row*64 + kb16);
            bl[nn]=*(const short8_t*)(smem + 2*AB + BB + row*64 + kb16);
        }
        #pragma unroll
        for(int m=0;m<MF;++m)
        #pragma unroll
        for(int nn=0;nn<NF;++nn){
            acc[m][nn]=__builtin_amdgcn_mfma_f32_16x16x32_bf16(ah[m],bh[nn],acc[m][nn],0,0,0);
            acc[m][nn]=__builtin_amdgcn_mfma_f32_16x16x32_bf16(ah[m],bl[nn],acc[m][nn],0,0,0);
            acc[m][nn]=__builtin_amdgcn_mfma_f32_16x16x32_bf16(al[m],bh[nn],acc[m][nn],0,0,0);
        }
        __syncthreads();
    }
}

// ---------------- pre-pass: transpose+split W[a][q] -> WhiT/WloT[q][a<256] ----------------
__global__ __launch_bounds__(256) void k_splitWT(const float* __restrict__ W,
        u16* __restrict__ WhiT, u16* __restrict__ WloT)
{
    __shared__ float tile[64][65];
    const int tid=threadIdx.x;
    const int q0=blockIdx.x*64, a0=blockIdx.y*64;
    const int tq=tid&63, ta=tid>>6;
    #pragma unroll
    for(int r=0;r<16;++r){
        int a=a0 + r*4 + ta;
        int q=q0 + tq;
        tile[r*4+ta][tq] = (q<Q_) ? W[(size_t)a*Q_ + q] : 0.f;
    }
    __syncthreads();
    #pragma unroll
    for(int r=0;r<16;++r){
        int qlocal=r*4+ta;
        int q=q0+qlocal, a=a0+tq;
        float v=tile[tq][qlocal];
        size_t addr=(size_t)q*256 + a;
        u16 h=f2bf(v);
        WhiT[addr]=h;
        WloT[addr]=f2bf(v - bf2f(h));
    }
}

__global__ __launch_bounds__(256) void k_split(const float* __restrict__ in,
        u16* __restrict__ hi, u16* __restrict__ lo, int n)
{
    int idx=blockIdx.x*256+threadIdx.x;
    if(idx<n){ float v=in[idx]; u16 h=f2bf(v); hi[idx]=h; lo[idx]=f2bf(v - bf2f(h)); }
}

// ---------------- Stage 1: T1[i][c][b] = sum_a l1p[i,a]*W[a][b*257+c] ----------------
// Grid (bblk=4, c=257). Block: M=160(i) x N=64(b) x K=256(a). Store b-contiguous.
__global__ __launch_bounds__(256,2) void k_stage1(
    const u16* __restrict__ l1hi, const u16* __restrict__ l1lo,
    const u16* __restrict__ WhiT, const u16* __restrict__ WloT,
    const float* __restrict__ W,
    u16* __restrict__ T1hi, u16* __restrict__ T1lo)
{
    constexpr int MF=5, NF=2;
    __shared__ __attribute__((aligned(64))) unsigned char smem[(32*MF+32*NF)*128];
    const int tid=threadIdx.x, lane=tid&63, wv=tid>>6, wm=wv>>1, wn=wv&1;
    const int b0=blockIdx.x*64;
    const int c =blockIdx.y;

    f32x4 acc[MF][NF];
    #pragma unroll
    for(int nn=0;nn<NF;++nn){
        int b=b0 + wn*32 + nn*16 + (lane&15);
        float v=W[(size_t)256*Q_ + (size_t)b*DP_ + c];   // bias row a=256 (b<=255 -> q<Q_)
        #pragma unroll
        for(int m=0;m<MF;++m) acc[m][nn]=(f32x4){v,v,v,v};
    }

    gemm_core<MF,NF>(l1hi, l1lo, 512,
                     WhiT + ((size_t)b0*DP_ + c)*256,
                     WloT + ((size_t)b0*DP_ + c)*256, DP_*512,
                     smem, acc);

    #pragma unroll
    for(int m=0;m<MF;++m){
        int iRow=wm*80 + m*16 + (lane>>4)*4;
        #pragma unroll
        for(int nn=0;nn<NF;++nn){
            int b=b0 + wn*32 + nn*16 + (lane&15);
            #pragma unroll
            for(int r=0;r<4;++r){
                size_t addr=(size_t)(iRow+r)*T1IS_ + (size_t)c*T1B_ + b;
                split_store(acc[m][nn][r], T1hi, T1lo, addr);
            }
        }
    }
}

// ---------------- Stage 1 bias col: T1bias[i][c] = sum_a l1p[i,a]*W[a][256*257+c] (f32) ----
__global__ __launch_bounds__(256,2) void k_stage1bias(
    const u16* __restrict__ l1hi, const u16* __restrict__ l1lo,
    const u16* __restrict__ WhiT, const u16* __restrict__ WloT,
    const float* __restrict__ W,
    float* __restrict__ T1bias)
{
    constexpr int MF=5, NF=2;
    __shared__ __attribute__((aligned(64))) unsigned char smem[(32*MF+32*NF)*128];
    const int tid=threadIdx.x, lane=tid&63, wv=tid>>6, wm=wv>>1, wn=wv&1;
    const int c0=blockIdx.x*64;

    f32x4 acc[MF][NF];
    #pragma unroll
    for(int nn=0;nn<NF;++nn){
        int c=c0 + wn*32 + nn*16 + (lane&15);
        float v=(c<DP_) ? W[(size_t)256*Q_ + (size_t)256*DP_ + c] : 0.f;  // W[256][256][c]
        #pragma unroll
        for(int m=0;m<MF;++m) acc[m][nn]=(f32x4){v,v,v,v};
    }

    gemm_core<MF,NF>(l1hi, l1lo, 512,
                     WhiT + ((size_t)256*DP_ + c0)*256,
                     WloT + ((size_t)256*DP_ + c0)*256, 512,
                     smem, acc);

    #pragma unroll
    for(int m=0;m<MF;++m){
        int iRow=wm*80 + m*16 + (lane>>4)*4;
        #pragma unroll
        for(int nn=0;nn<NF;++nn){
            int c=c0 + wn*32 + nn*16 + (lane&15);
            if(c<DP_){
                #pragma unroll
                for(int r=0;r<4;++r)
                    T1bias[(size_t)(iRow+r)*TBS_ + c]=acc[m][nn][r];
            }
        }
    }
}

// ---------------- Stage 2: T2[(i,j)][c] = sum_b l2p[j,b]*T1[i][c][b] ----------------
template<int NF>
__global__ __launch_bounds__(256,2) void k_stage2(
    const u16* __restrict__ l2hi, const u16* __restrict__ l2lo,
    const u16* __restrict__ T1hi, const u16* __restrict__ T1lo,
    const float* __restrict__ T1bias,
    u16* __restrict__ T2hi, u16* __restrict__ T2lo, int c0base)
{
    constexpr int MF=5;
    __shared__ __attribute__((aligned(64))) unsigned char smem[(32*MF+32*NF)*128];
    const int tid=threadIdx.x, lane=tid&63, wv=tid>>6, wm=wv>>1, wn=wv&1;
    const int i=blockIdx.y;
    const int c0=c0base + blockIdx.x*32*NF;

    f32x4 acc[MF][NF];
    #pragma unroll
    for(int nn=0;nn<NF;++nn){
        int c=c0 + wn*16*NF + nn*16 + (lane&15);
        float v=T1bias[(size_t)i*TBS_ + c];                 // bias b=256 (f32, exact)
        #pragma unroll
        for(int m=0;m<MF;++m) acc[m][nn]=(f32x4){v,v,v,v};
    }

    gemm_core<MF,NF>(l2hi, l2lo, 512,
                     T1hi + (size_t)i*T1IS_ + (size_t)c0*T1B_,
                     T1lo + (size_t)i*T1IS_ + (size_t)c0*T1B_, T1B_*2,
                     smem, acc);

    #pragma unroll
    for(int m=0;m<MF;++m){
        int j0=wm*80 + m*16 + (lane>>4)*4;
        #pragma unroll
        for(int nn=0;nn<NF;++nn){
            int c=c0 + wn*16*NF + nn*16 + (lane&15);
            if(c<DP_){
                #pragma unroll
                for(int r=0;r<4;++r){
                    size_t addr=(size_t)(i*L_ + j0 + r)*T2S_ + c;
                    split_store(acc[m][nn][r], T2hi, T2lo, addr);
                }
            }
        }
    }
}

// ---------------- Stage 3: out[(i,j)][k] = sum_c T2[(i,j)][c]*l3p[k,c] ----------------
__global__ __launch_bounds__(256,2) void k_stage3(
    const u16* __restrict__ T2hi, const u16* __restrict__ T2lo,
    const u16* __restrict__ l3hi, const u16* __restrict__ l3lo,
    float* __restrict__ outp)
{
    constexpr int MF=4, NF=5;
    __shared__ __attribute__((aligned(64))) unsigned char smem[(32*MF+32*NF)*128];
    const int tid=threadIdx.x, lane=tid&63, wv=tid>>6, wm=wv>>1, wn=wv&1;
    const int ij0=blockIdx.x*128;

    f32x4 acc[MF][NF];
    #pragma unroll
    for(int m=0;m<MF;++m){
        float v[4];
        #pragma unroll
        for(int r=0;r<4;++r){
            int row=ij0 + wm*64 + m*16 + (lane>>4)*4 + r;
            size_t ba=(size_t)row*T2S_ + 256;               // bias c=256
            v[r]=bf2f(T2hi[ba]) + bf2f(T2lo[ba]);
        }
        #pragma unroll
        for(int nn=0;nn<NF;++nn) acc[m][nn]=(f32x4){v[0],v[1],v[2],v[3]};
    }

    gemm_core<MF,NF>(T2hi + (size_t)ij0*T2S_, T2lo + (size_t)ij0*T2S_, T2S_*2,
                     l3hi, l3lo, 512,
                     smem, acc);

    #pragma unroll
    for(int m=0;m<MF;++m){
        #pragma unroll
        for(int nn=0;nn<NF;++nn){
            int k=wn*80 + nn*16 + (lane&15);
            #pragma unroll
            for(int r=0;r<4;++r){
                int ij=ij0 + wm*64 + m*16 + (lane>>4)*4 + r;
                outp[(size_t)ij*L_ + k]=acc[m][nn][r];
            }
        }
    }
}

extern "C" void kernel_launch(void* const* d_in, const int* in_sizes, int n_in,
                              void* d_out, int out_size, void* d_ws, size_t ws_size,
                              hipStream_t stream) {
    const float* l1=(const float*)d_in[0];
    const float* l2=(const float*)d_in[1];
    const float* l3=(const float*)d_in[2];
    const float* W =(const float*)d_in[3];
    float* outp=(float*)d_out;
    (void)ws_size; (void)in_sizes; (void)n_in; (void)out_size;

    u16* p=(u16*)d_ws;
    u16* WhiT=p; p+=(size_t)QT_*256;
    u16* WloT=p; p+=(size_t)QT_*256;
    u16* l1hi=p; p+=640*256;  u16* l1lo=p; p+=640*256;
    u16* l2hi=p; p+=640*256;  u16* l2lo=p; p+=640*256;
    u16* l3hi=p; p+=640*256;  u16* l3lo=p; p+=640*256;
    u16* T1hi=p; p+=(size_t)L_*T1IS_;  u16* T1lo=p; p+=(size_t)L_*T1IS_;
    u16* T2hi=p; p+=(size_t)IJ_*T2S_;  u16* T2lo=p; p+=(size_t)IJ_*T2S_;
    float* T1bias=(float*)p;           p+=(size_t)L_*TBS_*2;

    k_splitWT<<<dim3(QT_/64, 4), 256, 0, stream>>>(W, WhiT, WloT);
    k_split<<<640, 256, 0, stream>>>(l1, l1hi, l1lo, 640*256);
    k_split<<<640, 256, 0, stream>>>(l2, l2hi, l2lo, 640*256);
    k_split<<<640, 256, 0, stream>>>(l3, l3hi, l3lo, 640*256);

    for(int n=0;n<4;++n){
        const size_t ofs=(size_t)n*L_*D_;
        k_stage1<<<dim3(4,257), 256, 0, stream>>>(l1hi+ofs, l1lo+ofs, WhiT, WloT, W, T1hi, T1lo);
        k_stage1bias<<<5, 256, 0, stream>>>(l1hi+ofs, l1lo+ofs, WhiT, WloT, W, T1bias);
        k_stage2<4><<<dim3(2,L_), 256, 0, stream>>>(l2hi+ofs, l2lo+ofs, T1hi, T1lo, T1bias, T2hi, T2lo, 0);
        k_stage2<1><<<dim3(1,L_), 256, 0, stream>>>(l2hi+ofs, l2lo+ofs, T1hi, T1lo, T1bias, T2hi, T2lo, 256);
        k_stage3<<<IJ_/128, 256, 0, stream>>>(T2hi, T2lo, l3hi+ofs, l3lo+ofs, outp + (size_t)n*IJ_*L_);
    }
}

// Round 4
// 445.412 us; speedup vs baseline: 3.8422x; 1.0936x over previous
//
#include <hip/hip_runtime.h>

#define L_    160
#define D_    256
#define DP_   257
#define Q_    66049            // DP*DP
#define WTR_  66176            // WT rows alloc (>= Q_)
#define TBS_  260              // T1bias row stride (f32)
#define IJ_   25600

typedef unsigned short u16;
typedef unsigned int   u32;
typedef __attribute__((ext_vector_type(8))) short short8_t;  // 8 bf16 (4 VGPR)
typedef __attribute__((ext_vector_type(4))) float f32x4;     // acc frag

__device__ __forceinline__ float bf2f(u16 u){ union{u32 i; float f;} x; x.i=((u32)u)<<16; return x.f; }
__device__ __forceinline__ u16 f2bf(float f){ u32 u=__float_as_uint(f); return (u16)((u + 0x7FFFu + ((u>>16)&1u))>>16); }
__device__ __forceinline__ u32 pack2(float a, float b){ return (u32)f2bf(a) | ((u32)f2bf(b)<<16); }
__device__ __forceinline__ void gload16(const void* g, void* l){
    __builtin_amdgcn_global_load_lds((const __attribute__((address_space(1))) u32*)g,
                                     (__attribute__((address_space(3))) u32*)l, 16, 0, 0);
}

// ---------------- shared MFMA core: C[M][N] += A[M][K=256] * B[K][N] ----------------
// A rows (M) and B rows (N) stored k-contiguous: each row = [hi 512B | lo 512B], so
// pass Alo = Ahi+256 (u16) with shared byte stride. Split-bf16: 3 MFMAs per frag pair.
template<int MF,int NF>
__device__ __forceinline__ void gemm_core(
    const u16* Ahi, const u16* Alo, int aStrideB,
    const u16* Bhi, const u16* Blo, int bStrideB,
    unsigned char* smem, f32x4 (&acc)[MF][NF])
{
    constexpr int AB = 32*MF*64;               // bytes of one A array in LDS
    constexpr int BB = 32*NF*64;
    constexpr int SLOTS = (2*AB+2*BB)/4096;    // 16B chunks per thread per K-tile
    const int tid=threadIdx.x, lane=tid&63, wv=tid>>6;
    const int wm=wv>>1, wn=wv&1;

    const unsigned char* src[SLOTS];
    #pragma unroll
    for(int s=0;s<SLOTS;++s){
        int byte=(s*256+tid)*16;
        int local; const unsigned char* base; int strideB;
        if(byte<AB)            { local=byte;          base=(const unsigned char*)Ahi; strideB=aStrideB; }
        else if(byte<2*AB)     { local=byte-AB;       base=(const unsigned char*)Alo; strideB=aStrideB; }
        else if(byte<2*AB+BB)  { local=byte-2*AB;     base=(const unsigned char*)Bhi; strideB=bStrideB; }
        else                   { local=byte-2*AB-BB;  base=(const unsigned char*)Blo; strideB=bStrideB; }
        int row=local>>6, ch=(local>>4)&3;
        src[s]=base + (size_t)row*strideB + ch*16;
    }
    const int kb16=(lane>>4)*16;
    for(int t=0;t<8;++t){
        #pragma unroll
        for(int s=0;s<SLOTS;++s){ gload16(src[s], smem + s*4096 + wv*1024); src[s]+=64; }
        __syncthreads();   // compiler drains vmcnt(0) before barrier -> LDS ready
        short8_t ah[MF], al[MF], bh[NF], bl[NF];
        #pragma unroll
        for(int m=0;m<MF;++m){
            int row=wm*16*MF + m*16 + (lane&15);
            ah[m]=*(const short8_t*)(smem + row*64 + kb16);
            al[m]=*(const short8_t*)(smem + AB + row*64 + kb16);
        }
        #pragma unroll
        for(int nn=0;nn<NF;++nn){
            int row=wn*16*NF + nn*16 + (lane&15);
            bh[nn]=*(const short8_t*)(smem + 2*AB + row*64 + kb16);
            bl[nn]=*(const short8_t*)(smem + 2*AB + BB + row*64 + kb16);
        }
        #pragma unroll
        for(int m=0;m<MF;++m)
        #pragma unroll
        for(int nn=0;nn<NF;++nn){
            acc[m][nn]=__builtin_amdgcn_mfma_f32_16x16x32_bf16(ah[m],bh[nn],acc[m][nn],0,0,0);
            acc[m][nn]=__builtin_amdgcn_mfma_f32_16x16x32_bf16(ah[m],bl[nn],acc[m][nn],0,0,0);
            acc[m][nn]=__builtin_amdgcn_mfma_f32_16x16x32_bf16(al[m],bh[nn],acc[m][nn],0,0,0);
        }
        __syncthreads();
    }
}

// ---------- pre-pass: W[a][q=b*257+c] -> WT[r=c*257+b][hi a|lo a] (split, permuted) ----------
__global__ __launch_bounds__(256) void k_splitWT(const float* __restrict__ W,
        u32* __restrict__ WT32)
{
    __shared__ float tile[128][65];
    const int tid=threadIdx.x;
    const int q0=blockIdx.x*64, a0=blockIdx.y*128;
    #pragma unroll
    for(int w=0;w<32;++w){                    // read 128a x 64q, q-coalesced
        int idx=w*256+tid;
        int ar=idx>>6, qc=idx&63;
        int q=q0+qc;
        tile[ar][qc] = (q<Q_) ? W[(size_t)(a0+ar)*Q_ + q] : 0.f;
    }
    __syncthreads();
    #pragma unroll
    for(int w=0;w<16;++w){                    // write 64r x 64 u32-pairs, packed
        int idx=w*256+tid;
        int rq=idx>>6, pr=idx&63;
        int q=q0+rq;
        if(q<Q_){
            float v0=tile[2*pr][rq], v1=tile[2*pr+1][rq];
            u32 b=(u32)q/257u, c=(u32)q-b*257u;
            size_t r=(size_t)c*257u+b;
            u16 h0=f2bf(v0), h1=f2bf(v1);
            WT32[r*256 + (a0>>1) + pr]       = (u32)h0 | ((u32)h1<<16);
            WT32[r*256 + 128 + (a0>>1) + pr] = pack2(v0-bf2f(h0), v1-bf2f(h1));
        }
    }
}

// ---------- pre-pass: split l1/l2/l3 rows -> [hi 256|lo 256] u16 rows ----------
__global__ __launch_bounds__(256) void k_split3(
        const float* __restrict__ l1, const float* __restrict__ l2, const float* __restrict__ l3,
        u32* __restrict__ o1, u32* __restrict__ o2, u32* __restrict__ o3)
{
    const int bid=blockIdx.x;
    const int which=bid/320, rp=bid%320;
    const float* in = which==0 ? l1 : (which==1 ? l2 : l3);
    u32* out = which==0 ? o1 : (which==1 ? o2 : o3);
    const int row=rp*2 + (threadIdx.x>>7);
    const int col2=threadIdx.x&127;
    float2 v=*(const float2*)&in[(size_t)row*256 + col2*2];
    u16 h0=f2bf(v.x), h1=f2bf(v.y);
    out[(size_t)row*256 + col2]       = (u32)h0 | ((u32)h1<<16);
    out[(size_t)row*256 + 128 + col2] = pack2(v.x-bf2f(h0), v.y-bf2f(h1));
}

// ---------------- Stage 1: T1[i*257+c][b] = sum_a l1p[i,a]*W[a,b,c]; + T1bias ----------------
// grid (3, 258): y<257,x<2 -> main N=128 b-tile; y==257 -> bias cols (b=256) f32
__global__ __launch_bounds__(256,2) void k_stage1(
    const u16* __restrict__ l1s, const u16* __restrict__ WT,
    const float* __restrict__ W,
    u16* __restrict__ T1, float* __restrict__ T1bias)
{
    constexpr int MF=5, NF=4;
    __shared__ __attribute__((aligned(64))) unsigned char smem[(32*MF+32*NF)*128];
    const int tid=threadIdx.x, lane=tid&63, wv=tid>>6, wm=wv>>1, wn=wv&1;
    const int x=blockIdx.x, y=blockIdx.y;

    f32x4 acc[MF][NF];
    if(y<257){
        if(x>=2) return;
        const int c=y, b0=x*128;
        #pragma unroll
        for(int nn=0;nn<NF;++nn){
            int b=b0 + wn*64 + nn*16 + (lane&15);
            float v=W[(size_t)256*Q_ + (size_t)b*DP_ + c];          // bias row a=256
            #pragma unroll
            for(int m=0;m<MF;++m) acc[m][nn]=(f32x4){v,v,v,v};
        }
        const u16* Bh=WT + ((size_t)c*257 + b0)*512;
        gemm_core<MF,NF>(l1s, l1s+256, 1024, Bh, Bh+256, 1024, smem, acc);
        #pragma unroll
        for(int m=0;m<MF;++m){
            int iRow=wm*80 + m*16 + (lane>>4)*4;
            #pragma unroll
            for(int nn=0;nn<NF;++nn){
                int b=b0 + wn*64 + nn*16 + (lane&15);
                #pragma unroll
                for(int r=0;r<4;++r){
                    size_t rowb=((size_t)(iRow+r)*257 + c)*512;
                    float v=acc[m][nn][r];
                    u16 h=f2bf(v);
                    T1[rowb + b]       = h;
                    T1[rowb + 256 + b] = f2bf(v-bf2f(h));
                }
            }
        }
    } else {
        const int c0=(x==2)?129:x*128;                              // overlap tile: identical values
        #pragma unroll
        for(int nn=0;nn<NF;++nn){
            int c=c0 + wn*64 + nn*16 + (lane&15);
            float v=W[(size_t)256*Q_ + (size_t)256*DP_ + c];        // W[256][256][c]
            #pragma unroll
            for(int m=0;m<MF;++m) acc[m][nn]=(f32x4){v,v,v,v};
        }
        const u16* Bh=WT + ((size_t)c0*257 + 256)*512;
        gemm_core<MF,NF>(l1s, l1s+256, 1024, Bh, Bh+256, 257*1024, smem, acc);
        #pragma unroll
        for(int m=0;m<MF;++m){
            int iRow=wm*80 + m*16 + (lane>>4)*4;
            #pragma unroll
            for(int nn=0;nn<NF;++nn){
                int c=c0 + wn*64 + nn*16 + (lane&15);
                #pragma unroll
                for(int r=0;r<4;++r)
                    T1bias[(size_t)(iRow+r)*TBS_ + c]=acc[m][nn][r];
            }
        }
    }
}

// ---------------- Stage 2: T2[ij][c] = sum_b l2p[j,b]*T1[i*257+c][b]; + T2bias ----------------
// grid (3, 160): x<2 -> NF=4 c-tile {0,128}; x==2 -> NF=1 c0=225 (covers c=256 -> T2bias f32)
__global__ __launch_bounds__(256,2) void k_stage2(
    const u16* __restrict__ l2s, const u16* __restrict__ T1,
    const float* __restrict__ T1bias,
    u16* __restrict__ T2, float* __restrict__ T2bias)
{
    constexpr int MF=5;
    __shared__ __attribute__((aligned(64))) unsigned char smem[(32*MF+32*4)*128];
    const int tid=threadIdx.x, lane=tid&63, wv=tid>>6, wm=wv>>1, wn=wv&1;
    const int x=blockIdx.x, i=blockIdx.y;

    if(x<2){
        constexpr int NF=4;
        const int c0=x*128;
        f32x4 acc[MF][NF];
        #pragma unroll
        for(int nn=0;nn<NF;++nn){
            int c=c0 + wn*64 + nn*16 + (lane&15);
            float v=T1bias[(size_t)i*TBS_ + c];
            #pragma unroll
            for(int m=0;m<MF;++m) acc[m][nn]=(f32x4){v,v,v,v};
        }
        const u16* Bh=T1 + ((size_t)i*257 + c0)*512;
        gemm_core<MF,NF>(l2s, l2s+256, 1024, Bh, Bh+256, 1024, smem, acc);
        #pragma unroll
        for(int m=0;m<MF;++m){
            int j0=wm*80 + m*16 + (lane>>4)*4;
            #pragma unroll
            for(int nn=0;nn<NF;++nn){
                int c=c0 + wn*64 + nn*16 + (lane&15);
                #pragma unroll
                for(int r=0;r<4;++r){
                    size_t rowb=(size_t)(i*L_ + j0 + r)*512;
                    float v=acc[m][nn][r];
                    u16 h=f2bf(v);
                    T2[rowb + c]       = h;
                    T2[rowb + 256 + c] = f2bf(v-bf2f(h));
                }
            }
        }
    } else {
        constexpr int NF=1;
        const int c0=225;                                           // covers 225..256
        f32x4 acc[MF][NF];
        #pragma unroll
        for(int nn=0;nn<NF;++nn){
            int c=c0 + wn*16 + (lane&15);
            float v=T1bias[(size_t)i*TBS_ + c];
            #pragma unroll
            for(int m=0;m<MF;++m) acc[m][nn]=(f32x4){v,v,v,v};
        }
        const u16* Bh=T1 + ((size_t)i*257 + c0)*512;
        gemm_core<MF,NF>(l2s, l2s+256, 1024, Bh, Bh+256, 1024, smem, acc);
        #pragma unroll
        for(int m=0;m<MF;++m){
            int j0=wm*80 + m*16 + (lane>>4)*4;
            int c=c0 + wn*16 + (lane&15);
            #pragma unroll
            for(int r=0;r<4;++r){
                int ij=i*L_ + j0 + r;
                float v=acc[m][0][r];
                if(c<256){                                          // identical-value race with x=1
                    size_t rowb=(size_t)ij*512;
                    u16 h=f2bf(v);
                    T2[rowb + c]       = h;
                    T2[rowb + 256 + c] = f2bf(v-bf2f(h));
                } else {
                    T2bias[ij]=v;                                   // c==256, exact f32
                }
            }
        }
    }
}

// ---------------- Stage 3: out[ij][k] = sum_c T2[ij][c]*l3p[k,c] ----------------
__global__ __launch_bounds__(256,2) void k_stage3(
    const u16* __restrict__ T2, const float* __restrict__ T2bias,
    const u16* __restrict__ l3s, float* __restrict__ outp)
{
    constexpr int MF=4, NF=5;
    __shared__ __attribute__((aligned(64))) unsigned char smem[(32*MF+32*NF)*128];
    const int tid=threadIdx.x, lane=tid&63, wv=tid>>6, wm=wv>>1, wn=wv&1;
    const int ij0=blockIdx.x*128;

    f32x4 acc[MF][NF];
    #pragma unroll
    for(int m=0;m<MF;++m){
        float v[4];
        #pragma unroll
        for(int r=0;r<4;++r)
            v[r]=T2bias[ij0 + wm*64 + m*16 + (lane>>4)*4 + r];      // bias c=256
        #pragma unroll
        for(int nn=0;nn<NF;++nn) acc[m][nn]=(f32x4){v[0],v[1],v[2],v[3]};
    }

    const u16* Ah=T2 + (size_t)ij0*512;
    gemm_core<MF,NF>(Ah, Ah+256, 1024, l3s, l3s+256, 1024, smem, acc);

    #pragma unroll
    for(int m=0;m<MF;++m){
        #pragma unroll
        for(int nn=0;nn<NF;++nn){
            int k=wn*80 + nn*16 + (lane&15);
            #pragma unroll
            for(int r=0;r<4;++r){
                int ij=ij0 + wm*64 + m*16 + (lane>>4)*4 + r;
                outp[(size_t)ij*L_ + k]=acc[m][nn][r];
            }
        }
    }
}

extern "C" void kernel_launch(void* const* d_in, const int* in_sizes, int n_in,
                              void* d_out, int out_size, void* d_ws, size_t ws_size,
                              hipStream_t stream) {
    const float* l1=(const float*)d_in[0];
    const float* l2=(const float*)d_in[1];
    const float* l3=(const float*)d_in[2];
    const float* W =(const float*)d_in[3];
    float* outp=(float*)d_out;
    (void)ws_size; (void)in_sizes; (void)n_in; (void)out_size;

    u16* p=(u16*)d_ws;
    u16* WT =p;  p+=(size_t)WTR_*512;          // 67.8 MB
    u16* l1s=p;  p+=(size_t)640*512;
    u16* l2s=p;  p+=(size_t)640*512;
    u16* l3s=p;  p+=(size_t)640*512;
    u16* T1 =p;  p+=(size_t)160*257*512;       // 42.1 MB
    u16* T2 =p;  p+=(size_t)IJ_*512;           // 26.2 MB
    float* T1bias=(float*)p; p+=(size_t)L_*TBS_*2;
    float* T2bias=(float*)p; p+=(size_t)IJ_*2;

    k_splitWT<<<dim3(1034,2), 256, 0, stream>>>(W, (u32*)WT);
    k_split3<<<960, 256, 0, stream>>>(l1, l2, l3, (u32*)l1s, (u32*)l2s, (u32*)l3s);

    for(int n=0;n<4;++n){
        const size_t ro=(size_t)n*160*512;
        k_stage1<<<dim3(3,258), 256, 0, stream>>>(l1s+ro, WT, W, T1, T1bias);
        k_stage2<<<dim3(3,160), 256, 0, stream>>>(l2s+ro, T1, T1bias, T2, T2bias);
        k_stage3<<<200, 256, 0, stream>>>(T2, T2bias, l3s+ro, outp + (size_t)n*IJ_*L_);
    }
}

// Round 5
// 397.541 us; speedup vs baseline: 4.3048x; 1.1204x over previous
//
#include <hip/hip_runtime.h>

#define L_    160
#define D_    256
#define DP_   257
#define Q_    66049            // DP*DP
#define WTR_  66176            // WT rows alloc (>= Q_)
#define TBS_  260              // T1bias row stride (f32)
#define IJ_   25600

typedef unsigned short u16;
typedef unsigned int   u32;
typedef __attribute__((ext_vector_type(8))) short short8_t;  // 8 bf16 (4 VGPR)
typedef __attribute__((ext_vector_type(4))) float f32x4;     // acc frag

__device__ __forceinline__ float bf2f(u16 u){ union{u32 i; float f;} x; x.i=((u32)u)<<16; return x.f; }
__device__ __forceinline__ u16 f2bf(float f){ u32 u=__float_as_uint(f); return (u16)((u + 0x7FFFu + ((u>>16)&1u))>>16); }
__device__ __forceinline__ void gload16(const void* g, void* l){
    __builtin_amdgcn_global_load_lds((const __attribute__((address_space(1))) u32*)g,
                                     (__attribute__((address_space(3))) u32*)l, 16, 0, 0);
}

// ---------------- shared MFMA core: C[M][N] += A[M][K=256] * B[K][N] ----------------
// A rows (M) and B rows (N) stored k-contiguous: each row = [hi 512B | lo 512B], so
// pass Alo = Ahi+256 (u16) with shared byte stride. Split-bf16: 3 MFMAs per frag pair.
template<int MF,int NF>
__device__ __forceinline__ void gemm_core(
    const u16* Ahi, const u16* Alo, int aStrideB,
    const u16* Bhi, const u16* Blo, int bStrideB,
    unsigned char* smem, f32x4 (&acc)[MF][NF])
{
    constexpr int AB = 32*MF*64;               // bytes of one A array in LDS
    constexpr int BB = 32*NF*64;
    constexpr int SLOTS = (2*AB+2*BB)/4096;    // 16B chunks per thread per K-tile
    const int tid=threadIdx.x, lane=tid&63, wv=tid>>6;
    const int wm=wv>>1, wn=wv&1;

    const unsigned char* src[SLOTS];
    #pragma unroll
    for(int s=0;s<SLOTS;++s){
        int byte=(s*256+tid)*16;
        int local; const unsigned char* base; int strideB;
        if(byte<AB)            { local=byte;          base=(const unsigned char*)Ahi; strideB=aStrideB; }
        else if(byte<2*AB)     { local=byte-AB;       base=(const unsigned char*)Alo; strideB=aStrideB; }
        else if(byte<2*AB+BB)  { local=byte-2*AB;     base=(const unsigned char*)Bhi; strideB=bStrideB; }
        else                   { local=byte-2*AB-BB;  base=(const unsigned char*)Blo; strideB=bStrideB; }
        int row=local>>6, ch=(local>>4)&3;
        src[s]=base + (size_t)row*strideB + ch*16;
    }
    const int kb16=(lane>>4)*16;
    for(int t=0;t<8;++t){
        #pragma unroll
        for(int s=0;s<SLOTS;++s){ gload16(src[s], smem + s*4096 + wv*1024); src[s]+=64; }
        __syncthreads();   // compiler drains vmcnt(0) before barrier -> LDS ready
        short8_t ah[MF], al[MF], bh[NF], bl[NF];
        #pragma unroll
        for(int m=0;m<MF;++m){
            int row=wm*16*MF + m*16 + (lane&15);
            ah[m]=*(const short8_t*)(smem + row*64 + kb16);
            al[m]=*(const short8_t*)(smem + AB + row*64 + kb16);
        }
        #pragma unroll
        for(int nn=0;nn<NF;++nn){
            int row=wn*16*NF + nn*16 + (lane&15);
            bh[nn]=*(const short8_t*)(smem + 2*AB + row*64 + kb16);
            bl[nn]=*(const short8_t*)(smem + 2*AB + BB + row*64 + kb16);
        }
        #pragma unroll
        for(int m=0;m<MF;++m)
        #pragma unroll
        for(int nn=0;nn<NF;++nn){
            acc[m][nn]=__builtin_amdgcn_mfma_f32_16x16x32_bf16(ah[m],bh[nn],acc[m][nn],0,0,0);
            acc[m][nn]=__builtin_amdgcn_mfma_f32_16x16x32_bf16(ah[m],bl[nn],acc[m][nn],0,0,0);
            acc[m][nn]=__builtin_amdgcn_mfma_f32_16x16x32_bf16(al[m],bh[nn],acc[m][nn],0,0,0);
        }
        __syncthreads();
    }
}

// ---------- pre-pass: W[a][q=b*257+c] -> WT[r=c*257+b] rows [hi 256|lo 256] u16 ----------
// 64a x 64q tiles; LDS [64][65]: writes (qc=lane) bank (ar+lane)%32 free;
// reads tile[lane][rq] bank (lane+rq)%32 2-way free. Direct u16 stores, no packing.
__global__ __launch_bounds__(256) void k_splitWT(const float* __restrict__ W,
        u16* __restrict__ WT)
{
    __shared__ float tile[64][65];
    const int tid=threadIdx.x;
    const int q0=blockIdx.x*64, a0=blockIdx.y*64;
    #pragma unroll
    for(int w=0;w<16;++w){                    // read 64a x 64q, q-coalesced
        int idx=w*256+tid;
        int ar=idx>>6, qc=idx&63;
        int q=q0+qc;
        tile[ar][qc] = (q<Q_) ? W[(size_t)(a0+ar)*Q_ + q] : 0.f;
    }
    __syncthreads();
    const int lane=tid&63, wv=tid>>6;
    #pragma unroll
    for(int w=0;w<16;++w){                    // per wave: one q-column, 64 a's
        int rq=w*4+wv;
        int q=q0+rq;
        if(q<Q_){
            u32 b=(u32)q/257u, c=(u32)q-b*257u;
            size_t r=(size_t)c*257u+b;
            u16* dst=WT + r*512 + a0 + lane;
            float v=tile[lane][rq];
            u16 h=f2bf(v);
            dst[0]   = h;                     // hi half
            dst[256] = f2bf(v-bf2f(h));       // lo half
        }
    }
}

// ---------- pre-pass: split l1/l2/l3 rows -> [hi 256|lo 256] u16 rows ----------
__global__ __launch_bounds__(256) void k_split3(
        const float* __restrict__ l1, const float* __restrict__ l2, const float* __restrict__ l3,
        u32* __restrict__ o1, u32* __restrict__ o2, u32* __restrict__ o3)
{
    const int bid=blockIdx.x;
    const int which=bid/320, rp=bid%320;
    const float* in = which==0 ? l1 : (which==1 ? l2 : l3);
    u32* out = which==0 ? o1 : (which==1 ? o2 : o3);
    const int row=rp*2 + (threadIdx.x>>7);
    const int col2=threadIdx.x&127;
    float2 v=*(const float2*)&in[(size_t)row*256 + col2*2];
    u16 h0=f2bf(v.x), h1=f2bf(v.y);
    u16 g0=f2bf(v.x-bf2f(h0)), g1=f2bf(v.y-bf2f(h1));
    out[(size_t)row*256 + col2]       = (u32)h0 | ((u32)h1<<16);
    out[(size_t)row*256 + 128 + col2] = (u32)g0 | ((u32)g1<<16);
}

// ---------------- Stage 1: T1[i*257+c][b] = sum_a l1p[i,a]*W[a,b,c]; + T1bias ----------------
// 1D grid 517: bid<514 -> main (c=bid>>1, b0=(bid&1)*128); bid>=514 -> bias cols (b=256) f32,
// c0 in {0,128,129} (overlap tile identical values).
__global__ __launch_bounds__(256,2) void k_stage1(
    const u16* __restrict__ l1s, const u16* __restrict__ WT,
    const float* __restrict__ W,
    u16* __restrict__ T1, float* __restrict__ T1bias)
{
    constexpr int MF=5, NF=4;
    __shared__ __attribute__((aligned(64))) unsigned char smem[(32*MF+32*NF)*128];
    const int tid=threadIdx.x, lane=tid&63, wv=tid>>6, wm=wv>>1, wn=wv&1;
    const int bid=blockIdx.x;

    f32x4 acc[MF][NF];
    if(bid<514){
        const int c=bid>>1, b0=(bid&1)*128;
        #pragma unroll
        for(int nn=0;nn<NF;++nn){
            int b=b0 + wn*64 + nn*16 + (lane&15);
            float v=W[(size_t)256*Q_ + (size_t)b*DP_ + c];          // bias row a=256
            #pragma unroll
            for(int m=0;m<MF;++m) acc[m][nn]=(f32x4){v,v,v,v};
        }
        const u16* Bh=WT + ((size_t)c*257 + b0)*512;
        gemm_core<MF,NF>(l1s, l1s+256, 1024, Bh, Bh+256, 1024, smem, acc);
        #pragma unroll
        for(int m=0;m<MF;++m){
            int iRow=wm*80 + m*16 + (lane>>4)*4;
            #pragma unroll
            for(int nn=0;nn<NF;++nn){
                int b=b0 + wn*64 + nn*16 + (lane&15);
                #pragma unroll
                for(int r=0;r<4;++r){
                    size_t rowb=((size_t)(iRow+r)*257 + c)*512;
                    float v=acc[m][nn][r];
                    u16 h=f2bf(v);
                    T1[rowb + b]       = h;
                    T1[rowb + 256 + b] = f2bf(v-bf2f(h));
                }
            }
        }
    } else {
        const int t=bid-514;
        const int c0 = (t==0)?0:((t==1)?128:129);                   // overlap: identical values
        #pragma unroll
        for(int nn=0;nn<NF;++nn){
            int c=c0 + wn*64 + nn*16 + (lane&15);
            float v=W[(size_t)256*Q_ + (size_t)256*DP_ + c];        // W[256][256][c]
            #pragma unroll
            for(int m=0;m<MF;++m) acc[m][nn]=(f32x4){v,v,v,v};
        }
        const u16* Bh=WT + ((size_t)c0*257 + 256)*512;
        gemm_core<MF,NF>(l1s, l1s+256, 1024, Bh, Bh+256, 257*1024, smem, acc);
        #pragma unroll
        for(int m=0;m<MF;++m){
            int iRow=wm*80 + m*16 + (lane>>4)*4;
            #pragma unroll
            for(int nn=0;nn<NF;++nn){
                int c=c0 + wn*64 + nn*16 + (lane&15);
                #pragma unroll
                for(int r=0;r<4;++r)
                    T1bias[(size_t)(iRow+r)*TBS_ + c]=acc[m][nn][r];
            }
        }
    }
}

// ---------------- Stage 2: T2[ij][c] = sum_b l2p[j,b]*T1[i*257+c][b]; + T2bias ----------------
// grid (3,160): c0 in {0,128,130}; c<256 -> split store, c==256 -> T2bias f32, c==257 masked.
__global__ __launch_bounds__(256,2) void k_stage2(
    const u16* __restrict__ l2s, const u16* __restrict__ T1,
    const float* __restrict__ T1bias,
    u16* __restrict__ T2, float* __restrict__ T2bias)
{
    constexpr int MF=5, NF=4;
    __shared__ __attribute__((aligned(64))) unsigned char smem[(32*MF+32*NF)*128];
    const int tid=threadIdx.x, lane=tid&63, wv=tid>>6, wm=wv>>1, wn=wv&1;
    const int x=blockIdx.x, i=blockIdx.y;
    const int c0 = (x==0)?0:((x==1)?128:130);

    f32x4 acc[MF][NF];
    #pragma unroll
    for(int nn=0;nn<NF;++nn){
        int c=c0 + wn*64 + nn*16 + (lane&15);
        float v=(c<=256) ? T1bias[(size_t)i*TBS_ + c] : 0.f;
        #pragma unroll
        for(int m=0;m<MF;++m) acc[m][nn]=(f32x4){v,v,v,v};
    }
    const u16* Bh=T1 + ((size_t)i*257 + c0)*512;
    gemm_core<MF,NF>(l2s, l2s+256, 1024, Bh, Bh+256, 1024, smem, acc);

    #pragma unroll
    for(int m=0;m<MF;++m){
        int j0=wm*80 + m*16 + (lane>>4)*4;
        #pragma unroll
        for(int nn=0;nn<NF;++nn){
            int c=c0 + wn*64 + nn*16 + (lane&15);
            #pragma unroll
            for(int r=0;r<4;++r){
                int ij=i*L_ + j0 + r;
                float v=acc[m][nn][r];
                if(c<256){
                    size_t rowb=(size_t)ij*512;
                    u16 h=f2bf(v);
                    T2[rowb + c]       = h;
                    T2[rowb + 256 + c] = f2bf(v-bf2f(h));
                } else if(c==256){
                    T2bias[ij]=v;                                   // exact f32
                }
            }
        }
    }
}

// ---------------- Stage 3 (merged over n): out[n][ij][k] = sum_c T2n[ij][c]*l3p[k,c] ----------
__global__ __launch_bounds__(256,2) void k_stage3(
    const u16* __restrict__ T2all, const float* __restrict__ T2biasAll,
    const u16* __restrict__ l3s, float* __restrict__ outp)
{
    constexpr int MF=4, NF=5;
    __shared__ __attribute__((aligned(64))) unsigned char smem[(32*MF+32*NF)*128];
    const int tid=threadIdx.x, lane=tid&63, wv=tid>>6, wm=wv>>1, wn=wv&1;
    const int n=blockIdx.y;
    const int ij0=blockIdx.x*128;

    const u16*  T2  = T2all + (size_t)n*IJ_*512;
    const float* Tb = T2biasAll + (size_t)n*IJ_;
    const u16*  Bh  = l3s + (size_t)n*160*512;
    float* out      = outp + (size_t)n*IJ_*L_;

    f32x4 acc[MF][NF];
    #pragma unroll
    for(int m=0;m<MF;++m){
        float v[4];
        #pragma unroll
        for(int r=0;r<4;++r)
            v[r]=Tb[ij0 + wm*64 + m*16 + (lane>>4)*4 + r];          // bias c=256
        #pragma unroll
        for(int nn=0;nn<NF;++nn) acc[m][nn]=(f32x4){v[0],v[1],v[2],v[3]};
    }

    const u16* Ah=T2 + (size_t)ij0*512;
    gemm_core<MF,NF>(Ah, Ah+256, 1024, Bh, Bh+256, 1024, smem, acc);

    #pragma unroll
    for(int m=0;m<MF;++m){
        #pragma unroll
        for(int nn=0;nn<NF;++nn){
            int k=wn*80 + nn*16 + (lane&15);
            #pragma unroll
            for(int r=0;r<4;++r){
                int ij=ij0 + wm*64 + m*16 + (lane>>4)*4 + r;
                out[(size_t)ij*L_ + k]=acc[m][nn][r];
            }
        }
    }
}

extern "C" void kernel_launch(void* const* d_in, const int* in_sizes, int n_in,
                              void* d_out, int out_size, void* d_ws, size_t ws_size,
                              hipStream_t stream) {
    const float* l1=(const float*)d_in[0];
    const float* l2=(const float*)d_in[1];
    const float* l3=(const float*)d_in[2];
    const float* W =(const float*)d_in[3];
    float* outp=(float*)d_out;
    (void)ws_size; (void)in_sizes; (void)n_in; (void)out_size;

    u16* p=(u16*)d_ws;
    u16* WT =p;  p+=(size_t)WTR_*512;          // 67.8 MB
    u16* l1s=p;  p+=(size_t)640*512;
    u16* l2s=p;  p+=(size_t)640*512;
    u16* l3s=p;  p+=(size_t)640*512;
    u16* T1 =p;  p+=(size_t)160*257*512;       // 42.1 MB
    u16* T2 =p;  p+=(size_t)4*IJ_*512;         // 104.9 MB (x4 n)
    float* T1bias=(float*)p; p+=(size_t)L_*TBS_*2;
    float* T2bias=(float*)p; p+=(size_t)4*IJ_*2;

    k_splitWT<<<dim3(1033,4), 256, 0, stream>>>(W, WT);
    k_split3<<<960, 256, 0, stream>>>(l1, l2, l3, (u32*)l1s, (u32*)l2s, (u32*)l3s);

    for(int n=0;n<4;++n){
        const size_t ro=(size_t)n*160*512;
        k_stage1<<<517, 256, 0, stream>>>(l1s+ro, WT, W, T1, T1bias);
        k_stage2<<<dim3(3,160), 256, 0, stream>>>(l2s+ro, T1, T1bias,
                                                  T2 + (size_t)n*IJ_*512, T2bias + (size_t)n*IJ_);
    }
    k_stage3<<<dim3(200,4), 256, 0, stream>>>(T2, T2bias, l3s, outp);
}

// Round 6
// 395.877 us; speedup vs baseline: 4.3229x; 1.0042x over previous
//
#include <hip/hip_runtime.h>

#define L_    160
#define D_    256
#define DP_   257
#define Q_    66049            // DP*DP
#define WTR_  66176            // WT rows alloc (>= Q_)
#define TBS_  260              // T1bias row stride (f32)
#define IJ_   25600

typedef unsigned short u16;
typedef unsigned int   u32;
typedef __attribute__((ext_vector_type(8))) short short8_t;  // 8 bf16 (4 VGPR)
typedef __attribute__((ext_vector_type(4))) float f32x4;     // acc frag

__device__ __forceinline__ float bf2f(u16 u){ union{u32 i; float f;} x; x.i=((u32)u)<<16; return x.f; }
__device__ __forceinline__ u16 f2bf(float f){ u32 u=__float_as_uint(f); return (u16)((u + 0x7FFFu + ((u>>16)&1u))>>16); }
__device__ __forceinline__ void gload16(const void* g, void* l){
    __builtin_amdgcn_global_load_lds((const __attribute__((address_space(1))) u32*)g,
                                     (__attribute__((address_space(3))) u32*)l, 16, 0, 0);
}

// ---------------- shared MFMA core: C[M][N] += A[M][K=256] * B[K][N] ----------------
// 2-phase pipeline (T3-minimum): double-buffered LDS; STAGE(t+1) issued BEFORE the
// ds_read+MFMA of tile t; single __syncthreads per K-step (its vmcnt(0) drain waits
// only the residual latency after compute overlap). Rows = [hi 512B | lo 512B];
// split-bf16: 3 MFMAs per frag pair. setprio(1) around the MFMA cluster (T5).
template<int MF,int NF>
__device__ __forceinline__ void gemm_core(
    const u16* Ahi, const u16* Alo, int aStrideB,
    const u16* Bhi, const u16* Blo, int bStrideB,
    unsigned char* smem, f32x4 (&acc)[MF][NF])
{
    constexpr int AB = 32*MF*64;               // bytes of one A array in LDS (per half)
    constexpr int BB = 32*NF*64;
    constexpr int HALF = 2*AB+2*BB;
    constexpr int SLOTS = HALF/4096;           // 16B chunks per thread per K-tile
    const int tid=threadIdx.x, lane=tid&63, wv=tid>>6;
    const int wm=wv>>1, wn=wv&1;

    const unsigned char* src[SLOTS];
    #pragma unroll
    for(int s=0;s<SLOTS;++s){
        int byte=(s*256+tid)*16;
        int local; const unsigned char* base; int strideB;
        if(byte<AB)            { local=byte;          base=(const unsigned char*)Ahi; strideB=aStrideB; }
        else if(byte<2*AB)     { local=byte-AB;       base=(const unsigned char*)Alo; strideB=aStrideB; }
        else if(byte<2*AB+BB)  { local=byte-2*AB;     base=(const unsigned char*)Bhi; strideB=bStrideB; }
        else                   { local=byte-2*AB-BB;  base=(const unsigned char*)Blo; strideB=bStrideB; }
        int row=local>>6, ch=(local>>4)&3;
        src[s]=base + (size_t)row*strideB + ch*16;
    }

    // prologue: stage t=0 into half 0
    #pragma unroll
    for(int s=0;s<SLOTS;++s){ gload16(src[s], smem + s*4096 + wv*1024); src[s]+=64; }
    __syncthreads();

    const int kb16=(lane>>4)*16;
    #pragma unroll
    for(int t=0;t<8;++t){
        const unsigned char* base = smem + (t&1)*HALF;
        if(t<7){                                   // prefetch t+1 into other half
            unsigned char* nb = smem + ((t+1)&1)*HALF;
            #pragma unroll
            for(int s=0;s<SLOTS;++s){ gload16(src[s], nb + s*4096 + wv*1024); src[s]+=64; }
        }
        short8_t ah[MF], al[MF], bh[NF], bl[NF];
        #pragma unroll
        for(int m=0;m<MF;++m){
            int row=wm*16*MF + m*16 + (lane&15);
            ah[m]=*(const short8_t*)(base + row*64 + kb16);
            al[m]=*(const short8_t*)(base + AB + row*64 + kb16);
        }
        #pragma unroll
        for(int nn=0;nn<NF;++nn){
            int row=wn*16*NF + nn*16 + (lane&15);
            bh[nn]=*(const short8_t*)(base + 2*AB + row*64 + kb16);
            bl[nn]=*(const short8_t*)(base + 2*AB + BB + row*64 + kb16);
        }
        __builtin_amdgcn_s_setprio(1);
        #pragma unroll
        for(int m=0;m<MF;++m)
        #pragma unroll
        for(int nn=0;nn<NF;++nn){
            acc[m][nn]=__builtin_amdgcn_mfma_f32_16x16x32_bf16(ah[m],bh[nn],acc[m][nn],0,0,0);
            acc[m][nn]=__builtin_amdgcn_mfma_f32_16x16x32_bf16(ah[m],bl[nn],acc[m][nn],0,0,0);
            acc[m][nn]=__builtin_amdgcn_mfma_f32_16x16x32_bf16(al[m],bh[nn],acc[m][nn],0,0,0);
        }
        __builtin_amdgcn_s_setprio(0);
        __syncthreads();   // drains residual vmcnt of the prefetch; frees both halves
    }
}

// ---------- pre-pass: W[a][q=b*257+c] -> WT[r=c*257+b] rows [hi 256|lo 256] u16 ----------
// 128a x 64q tiles. LDS [q][a] pad130: write bank (2q+a)%32 2-way free; read float2
// a-pairs stride-8B standard. Stores: 64 lanes x u32 = 256B segments (hi and lo).
__global__ __launch_bounds__(256) void k_splitWT(const float* __restrict__ W,
        u32* __restrict__ WT32)
{
    __shared__ float tile[64][130];
    const int tid=threadIdx.x;
    const int q0=blockIdx.x*64, a0=blockIdx.y*128;
    #pragma unroll
    for(int w=0;w<32;++w){                    // read 128a x 64q, q-coalesced
        int idx=w*256+tid;
        int ar=idx>>6, qc=idx&63;
        int q=q0+qc;
        tile[qc][ar] = (q<Q_) ? W[(size_t)(a0+ar)*Q_ + q] : 0.f;
    }
    __syncthreads();
    const int lane=tid&63, wv=tid>>6;
    #pragma unroll
    for(int w=0;w<16;++w){                    // per wave: one q-column, 64 a-pairs
        int rq=w*4+wv;
        int q=q0+rq;
        if(q<Q_){
            u32 b=(u32)q/257u, c=(u32)q-b*257u;
            size_t r=(size_t)c*257u+b;
            float2 v=*(const float2*)&tile[rq][2*lane];
            u16 h0=f2bf(v.x), h1=f2bf(v.y);
            u32* dst=WT32 + r*256 + (a0>>1) + lane;
            dst[0]   = (u32)h0 | ((u32)h1<<16);
            dst[128] = (u32)f2bf(v.x-bf2f(h0)) | ((u32)f2bf(v.y-bf2f(h1))<<16);
        }
    }
}

// ---------- pre-pass: split l1/l2/l3 rows -> [hi 256|lo 256] u16 rows ----------
__global__ __launch_bounds__(256) void k_split3(
        const float* __restrict__ l1, const float* __restrict__ l2, const float* __restrict__ l3,
        u32* __restrict__ o1, u32* __restrict__ o2, u32* __restrict__ o3)
{
    const int bid=blockIdx.x;
    const int which=bid/320, rp=bid%320;
    const float* in = which==0 ? l1 : (which==1 ? l2 : l3);
    u32* out = which==0 ? o1 : (which==1 ? o2 : o3);
    const int row=rp*2 + (threadIdx.x>>7);
    const int col2=threadIdx.x&127;
    float2 v=*(const float2*)&in[(size_t)row*256 + col2*2];
    u16 h0=f2bf(v.x), h1=f2bf(v.y);
    u16 g0=f2bf(v.x-bf2f(h0)), g1=f2bf(v.y-bf2f(h1));
    out[(size_t)row*256 + col2]       = (u32)h0 | ((u32)h1<<16);
    out[(size_t)row*256 + 128 + col2] = (u32)g0 | ((u32)g1<<16);
}

// ------- Stage 1 (all n): T1[n][i*257+c][b] = sum_a l1p[n,i,a]*W[a,b,c]; + T1bias -------
// 2068 blocks; bijective XCD-chunk remap (m204) so the 4 n-blocks sharing one WT tile run
// consecutively on the SAME XCD -> WT L2-hot. newid = n + 4*y; y<514 main, y>=514 bias.
__global__ __launch_bounds__(256,2) void k_stage1(
    const u16* __restrict__ l1sAll, const u16* __restrict__ WT,
    const float* __restrict__ W,
    u16* __restrict__ T1all, float* __restrict__ T1biasAll)
{
    constexpr int MF=5, NF=4;
    __shared__ __attribute__((aligned(64))) unsigned char smem[2*(32*MF+32*NF)*128];
    const int tid=threadIdx.x, lane=tid&63, wv=tid>>6, wm=wv>>1, wn=wv&1;

    const int wg=blockIdx.x;
    const int qq=2068/8, rr=2068%8;                 // 258, 4
    const int xcd=wg&7, loc=wg>>3;
    const int newid = (xcd<rr) ? xcd*(qq+1)+loc : rr*(qq+1)+(xcd-rr)*qq+loc;
    const int n = newid & 3, y = newid >> 2;

    const u16* l1s   = l1sAll + (size_t)n*160*512;
    u16* T1          = T1all  + (size_t)n*160*257*512;
    float* T1bias    = T1biasAll + (size_t)n*160*TBS_;

    f32x4 acc[MF][NF];
    if(y<514){
        const int c=y>>1, b0=(y&1)*128;
        #pragma unroll
        for(int nn=0;nn<NF;++nn){
            int b=b0 + wn*64 + nn*16 + (lane&15);
            float v=W[(size_t)256*Q_ + (size_t)b*DP_ + c];          // bias row a=256
            #pragma unroll
            for(int m=0;m<MF;++m) acc[m][nn]=(f32x4){v,v,v,v};
        }
        const u16* Bh=WT + ((size_t)c*257 + b0)*512;
        gemm_core<MF,NF>(l1s, l1s+256, 1024, Bh, Bh+256, 1024, smem, acc);
        #pragma unroll
        for(int m=0;m<MF;++m){
            int iRow=wm*80 + m*16 + (lane>>4)*4;
            #pragma unroll
            for(int nn=0;nn<NF;++nn){
                int b=b0 + wn*64 + nn*16 + (lane&15);
                #pragma unroll
                for(int r=0;r<4;++r){
                    size_t rowb=((size_t)(iRow+r)*257 + c)*512;
                    float v=acc[m][nn][r];
                    u16 h=f2bf(v);
                    T1[rowb + b]       = h;
                    T1[rowb + 256 + b] = f2bf(v-bf2f(h));
                }
            }
        }
    } else {
        const int t=y-514;
        const int c0 = (t==0)?0:((t==1)?128:129);                   // overlap: identical values
        #pragma unroll
        for(int nn=0;nn<NF;++nn){
            int c=c0 + wn*64 + nn*16 + (lane&15);
            float v=W[(size_t)256*Q_ + (size_t)256*DP_ + c];        // W[256][256][c]
            #pragma unroll
            for(int m=0;m<MF;++m) acc[m][nn]=(f32x4){v,v,v,v};
        }
        const u16* Bh=WT + ((size_t)c0*257 + 256)*512;
        gemm_core<MF,NF>(l1s, l1s+256, 1024, Bh, Bh+256, 257*1024, smem, acc);
        #pragma unroll
        for(int m=0;m<MF;++m){
            int iRow=wm*80 + m*16 + (lane>>4)*4;
            #pragma unroll
            for(int nn=0;nn<NF;++nn){
                int c=c0 + wn*64 + nn*16 + (lane&15);
                #pragma unroll
                for(int r=0;r<4;++r)
                    T1bias[(size_t)(iRow+r)*TBS_ + c]=acc[m][nn][r];
            }
        }
    }
}

// ------- Stage 2 (n-pair p): T2[z][ij][c] = sum_b l2p[j,b]*T1[n][i*257+c][b]; + T2bias -------
// grid (3,160,2): n = 2p+z; c0 in {0,128,130}; c<256 split store, c==256 -> T2bias, 257 masked.
__global__ __launch_bounds__(256,2) void k_stage2(
    const u16* __restrict__ l2sAll, const u16* __restrict__ T1all,
    const float* __restrict__ T1biasAll,
    u16* __restrict__ T2pair, float* __restrict__ T2biasPair, int p)
{
    constexpr int MF=5, NF=4;
    __shared__ __attribute__((aligned(64))) unsigned char smem[2*(32*MF+32*NF)*128];
    const int tid=threadIdx.x, lane=tid&63, wv=tid>>6, wm=wv>>1, wn=wv&1;
    const int x=blockIdx.x, i=blockIdx.y, z=blockIdx.z;
    const int n=p*2+z;
    const int c0 = (x==0)?0:((x==1)?128:130);

    const u16* l2s      = l2sAll + (size_t)n*160*512;
    const u16* T1       = T1all  + (size_t)n*160*257*512;
    const float* T1bias = T1biasAll + (size_t)n*160*TBS_;
    u16* T2             = T2pair + (size_t)z*IJ_*512;
    float* T2bias       = T2biasPair + (size_t)z*IJ_;

    f32x4 acc[MF][NF];
    #pragma unroll
    for(int nn=0;nn<NF;++nn){
        int c=c0 + wn*64 + nn*16 + (lane&15);
        float v=(c<=256) ? T1bias[(size_t)i*TBS_ + c] : 0.f;
        #pragma unroll
        for(int m=0;m<MF;++m) acc[m][nn]=(f32x4){v,v,v,v};
    }
    const u16* Bh=T1 + ((size_t)i*257 + c0)*512;
    gemm_core<MF,NF>(l2s, l2s+256, 1024, Bh, Bh+256, 1024, smem, acc);

    #pragma unroll
    for(int m=0;m<MF;++m){
        int j0=wm*80 + m*16 + (lane>>4)*4;
        #pragma unroll
        for(int nn=0;nn<NF;++nn){
            int c=c0 + wn*64 + nn*16 + (lane&15);
            #pragma unroll
            for(int r=0;r<4;++r){
                int ij=i*L_ + j0 + r;
                float v=acc[m][nn][r];
                if(c<256){
                    size_t rowb=(size_t)ij*512;
                    u16 h=f2bf(v);
                    T2[rowb + c]       = h;
                    T2[rowb + 256 + c] = f2bf(v-bf2f(h));
                } else if(c==256){
                    T2bias[ij]=v;                                   // exact f32
                }
            }
        }
    }
}

// ------- Stage 3 (n-pair p): out[n][ij][k] = sum_c T2[z][ij][c]*l3p[n,k,c] -------
__global__ __launch_bounds__(256,2) void k_stage3(
    const u16* __restrict__ T2pair, const float* __restrict__ T2biasPair,
    const u16* __restrict__ l3sAll, float* __restrict__ outp, int p)
{
    constexpr int MF=4, NF=5;
    __shared__ __attribute__((aligned(64))) unsigned char smem[2*(32*MF+32*NF)*128];
    const int tid=threadIdx.x, lane=tid&63, wv=tid>>6, wm=wv>>1, wn=wv&1;
    const int z=blockIdx.y, n=p*2+z;
    const int ij0=blockIdx.x*128;

    const u16*  T2  = T2pair + (size_t)z*IJ_*512;
    const float* Tb = T2biasPair + (size_t)z*IJ_;
    const u16*  Bh  = l3sAll + (size_t)n*160*512;
    float* out      = outp + (size_t)n*IJ_*L_;

    f32x4 acc[MF][NF];
    #pragma unroll
    for(int m=0;m<MF;++m){
        float v[4];
        #pragma unroll
        for(int r=0;r<4;++r)
            v[r]=Tb[ij0 + wm*64 + m*16 + (lane>>4)*4 + r];          // bias c=256
        #pragma unroll
        for(int nn=0;nn<NF;++nn) acc[m][nn]=(f32x4){v[0],v[1],v[2],v[3]};
    }

    const u16* Ah=T2 + (size_t)ij0*512;
    gemm_core<MF,NF>(Ah, Ah+256, 1024, Bh, Bh+256, 1024, smem, acc);

    #pragma unroll
    for(int m=0;m<MF;++m){
        #pragma unroll
        for(int nn=0;nn<NF;++nn){
            int k=wn*80 + nn*16 + (lane&15);
            #pragma unroll
            for(int r=0;r<4;++r){
                int ij=ij0 + wm*64 + m*16 + (lane>>4)*4 + r;
                out[(size_t)ij*L_ + k]=acc[m][nn][r];
            }
        }
    }
}

extern "C" void kernel_launch(void* const* d_in, const int* in_sizes, int n_in,
                              void* d_out, int out_size, void* d_ws, size_t ws_size,
                              hipStream_t stream) {
    const float* l1=(const float*)d_in[0];
    const float* l2=(const float*)d_in[1];
    const float* l3=(const float*)d_in[2];
    const float* W =(const float*)d_in[3];
    float* outp=(float*)d_out;
    (void)ws_size; (void)in_sizes; (void)n_in; (void)out_size;

    u16* p=(u16*)d_ws;
    u16* WT =p;  p+=(size_t)WTR_*512;          // 67.8 MB; dead after stage1 -> T2pair aliases
    u16* l1s=p;  p+=(size_t)640*512;
    u16* l2s=p;  p+=(size_t)640*512;
    u16* l3s=p;  p+=(size_t)640*512;
    u16* T1all=p; p+=(size_t)4*160*257*512 + 512;  // 168.4 MB (+1 row pad for c0=130 overread)
    float* T1biasAll=(float*)p; p+=(size_t)4*L_*TBS_*2;
    float* T2biasPair=(float*)p; p+=(size_t)2*IJ_*2;
    u16* T2pair = WT;                          // 52.4 MB inside WT's 67.8 MB

    k_splitWT<<<dim3(1033,2), 256, 0, stream>>>(W, (u32*)WT);
    k_split3<<<960, 256, 0, stream>>>(l1, l2, l3, (u32*)l1s, (u32*)l2s, (u32*)l3s);

    k_stage1<<<2068, 256, 0, stream>>>(l1s, WT, W, T1all, T1biasAll);

    for(int pp=0;pp<2;++pp){
        k_stage2<<<dim3(3,160,2), 256, 0, stream>>>(l2s, T1all, T1biasAll, T2pair, T2biasPair, pp);
        k_stage3<<<dim3(200,2), 256, 0, stream>>>(T2pair, T2biasPair, l3s, outp, pp);
    }
}